// Round 7
// baseline (134.258 us; speedup 1.0000x reference)
//
#include <hip/hip_runtime.h>

// Simplex projection along last dim (n = 12288), rows = 4096, fp32.
// wp = max(x - tau, 0), wc = x - wp, tau solves sum(max(x-tau,0)) = Z.
//
// SINGLE PASS, WRITE-THEN-FIX: for every element, wp=0 / wc=x is correct
// UNLESS x > tau. Whenever the bootstrap threshold t in {2,3} validates
// (g(t)=S_t-t*C_t >= Z  <=>  t <= tau*), Michelot's iteration started from
// tau0=(S_t-Z)/C_t satisfies tau >= t >= 2 throughout. So elements <= 2.0
// can be stored FINAL during the load stream (wc=x, wp=0), and only the
// ~280 elements > 2.0 (value+index appended to LDS via ds_atomic) can need
// fixing. After the in-wave solve, scatter-rewrite the ~5 true actives.
//   -> one read + one write of each byte (576 MB irreducible), zero barriers,
//      ~40 VGPRs (no row kept in registers), whole grid resident, loads and
//      stores interleaved for the kernel's entire duration.
// Fallback (invalid bootstrap / LDS overflow / tau might be < 2): re-read row
// (cache-resident) and rewrite wp/wc fully. Never triggers for N(0,1) rows.

constexpr int   N_COLS = 12288;
constexpr int   WAVE   = 64;
constexpr int   WPB    = 4;                     // independent waves (rows) per block
constexpr int   BLOCK  = WAVE * WPB;            // 256
constexpr int   V4     = N_COLS / (WAVE * 4);   // 48 f32x4 per lane
constexpr float Z_LVL  = 1.0f;
constexpr int   CAP    = 512;                   // per-wave compaction capacity (mean 280, std 17)
constexpr float T2     = 2.0f;
constexpr float T3     = 3.0f;

typedef float f32x4 __attribute__((ext_vector_type(4)));

__device__ __forceinline__ float wsum(float v) {
#pragma unroll
  for (int off = 32; off >= 1; off >>= 1) v += __shfl_xor(v, off, 64);
  return v;
}
__device__ __forceinline__ int wsumi(int v) {
#pragma unroll
  for (int off = 32; off >= 1; off >>= 1) v += __shfl_xor(v, off, 64);
  return v;
}

__global__ __launch_bounds__(BLOCK) void simplex_writefix(
    const float* __restrict__ x, float* __restrict__ wp, float* __restrict__ wc,
    int rows) {

  const int lane = threadIdx.x & 63;
  const int wv   = threadIdx.x >> 6;
  const int row  = blockIdx.x * WPB + wv;
  if (row >= rows) return;

  const size_t base = (size_t)row * N_COLS;
  const f32x4* __restrict__ xin = reinterpret_cast<const f32x4*>(x + base);
  f32x4* __restrict__ wpo = reinterpret_cast<f32x4*>(wp + base);
  f32x4* __restrict__ wco = reinterpret_cast<f32x4*>(wc + base);

  __shared__ float s_act[WPB][CAP];
  __shared__ int   s_idx[WPB][CAP];
  __shared__ int   s_n[WPB];

  if (lane == 0) s_n[wv] = 0;
  asm volatile("s_waitcnt lgkmcnt(0)" ::: "memory");  // counter visible to own wave

  const f32x4 zero4 = {0.f, 0.f, 0.f, 0.f};

  float sAll = 0.f, s2 = 0.f, s3 = 0.f;
  int   c2 = 0, c3 = 0;
  bool  ovf = false;

  // ---- stream: load -> store provisional (wc=x, wp=0) -> stats + append ----
#pragma unroll 8
  for (int k = 0; k < V4; ++k) {
    f32x4 t = __builtin_nontemporal_load(&xin[lane + k * WAVE]);
    __builtin_nontemporal_store(t,     &wco[lane + k * WAVE]);
    __builtin_nontemporal_store(zero4, &wpo[lane + k * WAVE]);
#pragma unroll
    for (int j = 0; j < 4; ++j) {
      float e = t[j];
      sAll += e;
      if (e > T2) {
        s2 += e; ++c2;
        if (e > T3) { s3 += e; ++c3; }
        int slot = atomicAdd(&s_n[wv], 1);
        if (slot < CAP) {
          s_act[wv][slot] = e;
          s_idx[wv][slot] = 4 * (lane + k * WAVE) + j;
        } else {
          ovf = true;
        }
      }
    }
  }

  sAll = wsum(sAll);  s2 = wsum(s2);  s3 = wsum(s3);
  c2 = wsumi(c2);     c3 = wsumi(c3);
  ovf = (__ballot(ovf) != 0ull);

  // ---- bootstrap pick (wave-uniform): largest valid t ----
  float tau = 0.f;
  int   prev = 0;
  bool  ok = false;
  if (!ovf && c2 > 0) {
    if (c3 > 0 && (s3 - 3.f * (float)c3) >= Z_LVL + 0.01f) {
      tau = (s3 - Z_LVL) / (float)c3;  prev = c3;  ok = true;   // tau >= 3
    } else if ((s2 - 2.f * (float)c2) >= Z_LVL + 0.01f) {
      tau = (s2 - Z_LVL) / (float)c2;  prev = c2;  ok = true;   // tau >= 2
    }
  }

  asm volatile("s_waitcnt lgkmcnt(0)" ::: "memory");  // appends visible in-wave

  if (ok) {
    // ---- Michelot on the compacted >2.0 set (tau stays >= 2: set is complete) ----
    const int n = c2;
    for (int it = 0; it < CAP + 2; ++it) {
      float ps = 0.f; int pc = 0;
      for (int i = lane; i < n; i += WAVE) {
        float a = s_act[wv][i];
        bool  g = a > tau;
        ps += g ? a : 0.f;
        pc += g ? 1 : 0;
      }
      ps = wsum(ps);  pc = wsumi(pc);
      tau = (ps - Z_LVL) / (float)pc;
      if (pc == prev) break;   // set stable -> exact fixed point
      prev = pc;
    }
    // ---- fix up true actives (overwrite after streamed stores landed) ----
    asm volatile("s_waitcnt vmcnt(0)" ::: "memory");
    float* __restrict__ wps = wp + base;
    float* __restrict__ wcs = wc + base;
    for (int i = lane; i < n; i += WAVE) {
      float a = s_act[wv][i];
      if (a > tau) {
        int idx = s_idx[wv][i];
        wps[idx] = a - tau;
        wcs[idx] = tau;
      }
    }
  } else {
    // ---- fallback (rare/adversarial): solve by re-reading, rewrite fully ----
    tau = (sAll - Z_LVL) / (float)N_COLS;
    prev = N_COLS;
    for (int it = 0; it < 100; ++it) {
      float ps = 0.f; int pc = 0;
      for (int k = 0; k < V4; ++k) {
        f32x4 t = xin[lane + k * WAVE];
#pragma unroll
        for (int j = 0; j < 4; ++j) {
          bool g = t[j] > tau;
          ps += g ? t[j] : 0.f;
          pc += g ? 1 : 0;
        }
      }
      ps = wsum(ps);  pc = wsumi(pc);
      tau = (ps - Z_LVL) / (float)pc;
      if (pc == prev) break;
      prev = pc;
    }
    asm volatile("s_waitcnt vmcnt(0)" ::: "memory");
    for (int k = 0; k < V4; ++k) {
      f32x4 t = xin[lane + k * WAVE];
      f32x4 pv, cv;
#pragma unroll
      for (int j = 0; j < 4; ++j) {
        pv[j] = fmaxf(t[j] - tau, 0.f);
        cv[j] = t[j] - pv[j];
      }
      wpo[lane + k * WAVE] = pv;
      wco[lane + k * WAVE] = cv;
    }
  }
}

extern "C" void kernel_launch(void* const* d_in, const int* in_sizes, int n_in,
                              void* d_out, int out_size, void* d_ws, size_t ws_size,
                              hipStream_t stream) {
  const float* x = (const float*)d_in[0];
  const int rows = in_sizes[0] / N_COLS;

  float* wp = (float*)d_out;
  float* wc = wp + (size_t)rows * N_COLS;

  const int nblk = (rows + WPB - 1) / WPB;
  simplex_writefix<<<nblk, BLOCK, 0, stream>>>(x, wp, wc, rows);
}

// Round 8
// 116.209 us; speedup vs baseline: 1.1553x; 1.1553x over previous
//
#include <hip/hip_runtime.h>

// Simplex projection along last dim (n = 12288), rows = 4096, fp32.
// wp = max(x - tau, 0), wc = x - wp, tau solves sum(max(x-tau,0)) = Z.
//
// STRUCTURE (3 stream-ordered ops):
//   1. hipMemsetAsync(wp, 0)  -- 201 MB at pure-fill BW; wp=0 is exact for all
//      elements with x <= tau (99.96% of them).
//   2. main kernel, one wave per row, ZERO barriers, 2 streams only:
//      stream loop: load x (nt) -> store wc = x provisional (nt) -> sAll += e,
//      ballot-append the ~280 elements > 2.0 (value+index) to per-wave LDS
//      (wave-uniform SGPR counter, popc offsets -- NO atomics, NO divergent
//      branch in the common case). Then bootstrap-validate t in {2,3}
//      (g(t)=S_t-t*C_t >= Z  <=>  t <= tau*), Michelot on the LDS list
//      (~4 iters, ballot/shuffle only), s_waitcnt vmcnt(0), scatter-fix the
//      ~5 true actives: wp[idx] = a - tau (over memset zeros), wc[idx] = tau
//      (over own provisional store; same-wave same-address order via vmcnt(0),
//      pattern validated in round 7).
//   3. fallback (invalid bootstrap / LDS overflow): re-read row, full Michelot,
//      rewrite both outputs entirely. Never taken for N(0,1) rows.
//
// Michelot from subset start: if A0 = {x > t} with t <= tau*, then every
// iterate tau_k <= tau*, active sets stay within A0, tau_k increases to tau*;
// count-stable <=> exact fixed point. Validity g(t) >= Z <=> tau0 >= t.

constexpr int   N_COLS = 12288;
constexpr int   WAVE   = 64;
constexpr int   WPB    = 4;                     // waves (rows) per block
constexpr int   BLOCK  = WAVE * WPB;            // 256
constexpr int   V4     = N_COLS / (WAVE * 4);   // 48 f32x4 per lane
constexpr float Z_LVL  = 1.0f;
constexpr int   CAP    = 512;                   // per-wave list capacity (mean 280, sd 17)
constexpr float T2     = 2.0f;
constexpr float T3     = 3.0f;

typedef float f32x4 __attribute__((ext_vector_type(4)));

__device__ __forceinline__ float wsum(float v) {
#pragma unroll
  for (int off = 32; off >= 1; off >>= 1) v += __shfl_xor(v, off, 64);
  return v;
}
__device__ __forceinline__ int wsumi(int v) {
#pragma unroll
  for (int off = 32; off >= 1; off >>= 1) v += __shfl_xor(v, off, 64);
  return v;
}

__global__ __launch_bounds__(BLOCK) void simplex_fix(
    const float* __restrict__ x, float* __restrict__ wp, float* __restrict__ wc,
    int rows) {

  const int lane = threadIdx.x & 63;
  const int wv   = threadIdx.x >> 6;
  const int row  = blockIdx.x * WPB + wv;
  if (row >= rows) return;

  const size_t base = (size_t)row * N_COLS;
  const f32x4* __restrict__ xin = reinterpret_cast<const f32x4*>(x + base);
  f32x4* __restrict__ wco = reinterpret_cast<f32x4*>(wc + base);

  __shared__ float s_act[WPB][CAP];
  __shared__ int   s_idx[WPB][CAP];

  const unsigned long long lt_mask = (lane == 0) ? 0ull : (~0ull >> (64 - lane));

  float sAll = 0.f;
  int   n    = 0;      // wave-uniform list length (stays in SGPR)
  bool  ovf  = false;

  // ---- stream: load -> provisional wc=x -> sum + ballot-append (>2.0) ----
#pragma unroll 8
  for (int k = 0; k < V4; ++k) {
    f32x4 t = __builtin_nontemporal_load(&xin[lane + k * WAVE]);
    __builtin_nontemporal_store(t, &wco[lane + k * WAVE]);
#pragma unroll
    for (int j = 0; j < 4; ++j) {
      float e = t[j];
      sAll += e;
      unsigned long long m = __ballot(e > T2);
      if (m) {                                   // wave-uniform branch, rare
        int c = (int)__popcll(m);
        if (n + c <= CAP) {
          if (e > T2) {
            int o = n + (int)__popcll(m & lt_mask);
            s_act[wv][o] = e;
            s_idx[wv][o] = 4 * (lane + k * WAVE) + j;
          }
        } else {
          ovf = true;
        }
        n += c;
      }
    }
  }
  sAll = wsum(sAll);

  bool ok = !ovf && (n > 0);
  float tau = 0.f;
  int   prev = 0;

  if (ok) {
    asm volatile("s_waitcnt lgkmcnt(0)" ::: "memory");  // appends visible in-wave
    // ---- stats from the compacted list (n <= CAP <= 8 per lane) ----
    float s2 = 0.f, s3 = 0.f;
    int   c3 = 0;
    for (int i = lane; i < n; i += WAVE) {
      float a = s_act[wv][i];
      s2 += a;
      bool g3 = a > T3;
      s3 += g3 ? a : 0.f;
      c3 += g3 ? 1 : 0;
    }
    s2 = wsum(s2);  s3 = wsum(s3);  c3 = wsumi(c3);
    const int c2 = n;

    if (c3 > 0 && (s3 - 3.f * (float)c3) >= Z_LVL + 0.01f) {
      tau = (s3 - Z_LVL) / (float)c3;  prev = c3;           // tau >= 3
    } else if ((s2 - 2.f * (float)c2) >= Z_LVL + 0.01f) {
      tau = (s2 - Z_LVL) / (float)c2;  prev = c2;           // tau >= 2
    } else {
      ok = false;                                           // tau* < 2: fallback
    }

    if (ok) {
      // ---- Michelot on the list (active sets stay within {x>2}) ----
      for (int it = 0; it < CAP + 2; ++it) {
        float ps = 0.f; int pc = 0;
        for (int i = lane; i < n; i += WAVE) {
          float a = s_act[wv][i];
          bool  g = a > tau;
          ps += g ? a : 0.f;
          pc += g ? 1 : 0;
        }
        ps = wsum(ps);  pc = wsumi(pc);
        tau = (ps - Z_LVL) / (float)pc;
        if (pc == prev) break;                              // stable -> exact
        prev = pc;
      }
      // ---- scatter-fix true actives (after provisional stores land) ----
      asm volatile("s_waitcnt vmcnt(0)" ::: "memory");
      float* __restrict__ wps = wp + base;
      float* __restrict__ wcs = wc + base;
      for (int i = lane; i < n; i += WAVE) {
        float a = s_act[wv][i];
        if (a > tau) {
          int idx = s_idx[wv][i];
          wps[idx] = a - tau;                               // over memset zero
          wcs[idx] = tau;                                   // over provisional x
        }
      }
      return;
    }
  }

  // ---- fallback (adversarial data only): full Michelot + full rewrite ----
  {
    tau = (sAll - Z_LVL) / (float)N_COLS;
    prev = N_COLS;
    for (int it = 0; it < 100; ++it) {
      float ps = 0.f; int pc = 0;
      for (int k = 0; k < V4; ++k) {
        f32x4 t = xin[lane + k * WAVE];
#pragma unroll
        for (int j = 0; j < 4; ++j) {
          bool g = t[j] > tau;
          ps += g ? t[j] : 0.f;
          pc += g ? 1 : 0;
        }
      }
      ps = wsum(ps);  pc = wsumi(pc);
      tau = (ps - Z_LVL) / (float)pc;
      if (pc == prev) break;
      prev = pc;
    }
    asm volatile("s_waitcnt vmcnt(0)" ::: "memory");
    f32x4* __restrict__ wpo = reinterpret_cast<f32x4*>(wp + base);
    for (int k = 0; k < V4; ++k) {
      f32x4 t = xin[lane + k * WAVE];
      f32x4 pv, cv;
#pragma unroll
      for (int j = 0; j < 4; ++j) {
        pv[j] = fmaxf(t[j] - tau, 0.f);
        cv[j] = t[j] - pv[j];
      }
      wpo[lane + k * WAVE] = pv;
      wco[lane + k * WAVE] = cv;
    }
  }
}

extern "C" void kernel_launch(void* const* d_in, const int* in_sizes, int n_in,
                              void* d_out, int out_size, void* d_ws, size_t ws_size,
                              hipStream_t stream) {
  const float* x = (const float*)d_in[0];
  const int rows = in_sizes[0] / N_COLS;

  float* wp = (float*)d_out;
  float* wc = wp + (size_t)rows * N_COLS;

  // wp = 0 everywhere (exact for all inactive elements) at pure-fill BW.
  hipMemsetAsync(wp, 0, (size_t)rows * N_COLS * sizeof(float), stream);

  const int nblk = (rows + WPB - 1) / WPB;
  simplex_fix<<<nblk, BLOCK, 0, stream>>>(x, wp, wc, rows);
}